// Round 8
// baseline (174.511 us; speedup 1.0000x reference)
//
#include <hip/hip_runtime.h>
#include <hip/hip_fp16.h>

#define NBC 14
#define NAC 45
#define KF  52
#define RHO 0.05f
#define TT  4096
#define BB  64
#define CH  64           // output steps per chunk
#define WU  80           // warmup steps (measured contraction ~0.92/step -> err ~2e-5)
#define NCHUNK 64        // TT / CH
#define NTMAX (CH + WU)  // 144
#define XPAD  (NTMAX + 2)   // 146 halfs; 292B stride -> distinct banks lanes 0..13
#define RING  52
#define RW    45
#define LOG2E 1.44269504f

typedef __fp16 v2h __attribute__((ext_vector_type(2)));

// DPP row-rotate-right by J within 16-lane rows (pure VALU)
template<int J>
__device__ __forceinline__ int rot_i(int v) {
  return __builtin_amdgcn_update_dpp(0, v, 0x120 + J, 0xF, 0xF, true);
}
template<int J>
__device__ __forceinline__ float rotf(float v) {
  return __int_as_float(rot_i<J>(__float_as_int(v)));
}
template<int J>
__device__ __forceinline__ v2h rotpk(v2h v) {
  return __builtin_bit_cast(v2h, rot_i<J>(__builtin_bit_cast(int, v)));
}
template<int J>
__device__ __forceinline__ float swzf(float v) {
  return __int_as_float(__builtin_amdgcn_ds_swizzle(__float_as_int(v), (J << 10) | 0x1f));
}
__device__ __forceinline__ float xsum16(float v) {
#if __has_builtin(__builtin_amdgcn_permlane16_swap)
  typedef int i2 __attribute__((ext_vector_type(2)));
  i2 r = __builtin_amdgcn_permlane16_swap(__float_as_int(v), __float_as_int(v), false, false);
  return __int_as_float(r[0]) + __int_as_float(r[1]);
#else
  return v + swzf<16>(v);
#endif
}
__device__ __forceinline__ float xsum32(float v) {
#if __has_builtin(__builtin_amdgcn_permlane32_swap)
  typedef int i2 __attribute__((ext_vector_type(2)));
  i2 r = __builtin_amdgcn_permlane32_swap(__float_as_int(v), __float_as_int(v), false, false);
  return __int_as_float(r[0]) + __int_as_float(r[1]);
#else
  return v + __shfl_xor(v, 32);
#endif
}
__device__ __forceinline__ v2h pk2(float lo, float hi) {
#if __has_builtin(__builtin_amdgcn_cvt_pkrtz)
  return __builtin_bit_cast(v2h, __builtin_amdgcn_cvt_pkrtz(lo, hi));
#else
  v2h r; r[0] = (__fp16)lo; r[1] = (__fp16)hi; return r;
#endif
}
__device__ __forceinline__ float fdot2f(v2h a, v2h b, float c) {
#if __has_builtin(__builtin_amdgcn_fdot2)
  return __builtin_amdgcn_fdot2(a, b, c, false);
#else
  return fmaf((float)a[0], (float)b[0], fmaf((float)a[1], (float)b[1], c));
#endif
}
__device__ __forceinline__ float exp2_f(float x) {
#if __has_builtin(__builtin_amdgcn_exp2f)
  return __builtin_amdgcn_exp2f(x);
#else
  return exp2f(x);
#endif
}

// LDS pool layout (bytes):
//  [0, 4088)            xf fp16 [NBC][XPAD]
//  [4088, 8768)         u ring fp16 [RING][RW]   (overlaid by x slice during conv)
//  [8768, 9488)         ac staging  [4][NAC] f32
//  [9488, 10160)        yb/fb/yl staging [4][NBC] f32 x3
#define POOL_BYTES 10160

__global__ __launch_bounds__(64)
void bcn_kernel(const float* __restrict__ x,
                const float* __restrict__ bck,
                const float* __restrict__ lss,
                const float* __restrict__ soff,
                const float* __restrict__ lbaw,
                const float* __restrict__ ltr,
                const float* __restrict__ ltd,
                const float* __restrict__ lass,
                const float* __restrict__ asoff,
                const float* __restrict__ labw,
                const float* __restrict__ oscale,
                float* __restrict__ out)
{
  __shared__ __align__(16) char pool[POOL_BYTES];
  __half* xf_lds = (__half*)pool;                    // [NBC][XPAD]
  __half* u_ring = (__half*)(pool + 4088);           // [RING][RW]
  float*  x_lds  = (float*)(pool + 4088);            // overlay, 196 floats max
  float*  ac_st  = (float*)(pool + 8768);            // [4][NAC]
  float*  yb_st  = (float*)(pool + 9488);            // [4][NBC]
  float*  fb_st  = yb_st + 4 * NBC;
  float*  yl_st  = fb_st + 4 * NBC;

  const int lid   = threadIdx.x;
  const int c16   = lid & 15;          // slot within 16-lane row
  const int q     = lid >> 4;          // row / quadrant
  const int blk   = blockIdx.x;
  const int b     = blk >> 6;          // batch (NCHUNK=64)
  const int chunk = blk & 63;
  const int t0      = chunk * CH;
  const int warm    = (chunk == 0) ? 0 : WU;
  const int t_begin = t0 - warm;
  const int NT      = CH + warm;       // 64 (chunk 0) or 144

  // ---- probe DPP row_ror direction: srcl(j) = (c16 - delta*j) & 15 ----
  const int probe = __builtin_amdgcn_update_dpp(0, c16, 0x121, 0xF, 0xF, true);
  const int delta = (c16 - probe) & 15;   // 1 or 15, uniform across lanes

  // ---- load stimulus slice into overlay (causal zero pad at t<0) ----
  for (int p = lid; p < NT + KF - 1; p += 64) {
    int gt = t_begin - (KF - 1) + p;
    x_lds[p] = (gt >= 0) ? x[b * TT + gt] : 0.f;
  }
  __syncthreads();

  // ---- causal conv into xf_lds (fp16) ----
  for (int ib = 0; ib < ((NT + 63) >> 6); ++ib) {
    int tau = lid + (ib << 6);
    if (tau < NT) {
      float acc[NBC];
#pragma unroll
      for (int c = 0; c < NBC; ++c) acc[c] = 0.f;
#pragma unroll 4
      for (int k = 0; k < KF; ++k) {
        float xv = x_lds[tau + k];
#pragma unroll
        for (int c = 0; c < NBC; ++c) acc[c] = fmaf(bck[c * KF + k], xv, acc[c]);
      }
#pragma unroll
      for (int c = 0; c < NBC; ++c) xf_lds[c * XPAD + tau] = __float2half(acc[c]);
    }
  }
  __syncthreads();

  // ---- zero u ring (x slice is dead now) ----
  for (int i = lid; i < (RING * RW + 1) / 2; i += 64) ((unsigned int*)u_ring)[i] = 0u;
  __syncthreads();

  // ---- per-lane parameters ----
  float slope2 = 0.f, soff2 = 0.f, osc_c = 0.f;    // BC sigmoid in exp2 domain
  float pool_b = 1.f, pool_l = 1.f;
  float r1i = 0.f, r2i = 0.f, co1 = 0.f, co2 = 0.f, cn1 = 0.f, cn2 = 0.f;
  float Adrv2 = 0.f, Boff2 = 0.f;                  // AC sigmoid in exp2 domain
  v2h wfbp[8];   // fb packed weights
  v2h wup[8];    // u  packed weights
  float S1 = 0.f, S2 = 0.f;

#pragma unroll
  for (int j = 0; j < 8; ++j) { wfbp[j] = pk2(0.f, 0.f); wup[j] = pk2(0.f, 0.f); }

  if (c16 < NBC) {
    float sl = expf(lss[c16]);
    slope2 = sl * LOG2E;
    soff2  = soff[c16] * sl * LOG2E;
    osc_c  = oscale[c16];
  }
#pragma unroll
  for (int j = 0; j < 8; ++j) {
    int src = (c16 - delta * j) & 15;
    float wlo = 0.f, whi = 0.f;
    if (c16 < NBC) {
      int a0 = 16 * q + src;
      int a1 = 16 * q + (src ^ 8);
      if (a0 < NAC) wlo = -expf(labw[c16 * NAC + a0]);
      if (a1 < NAC) whi = -expf(labw[c16 * NAC + a1]);
    }
    wfbp[j] = pk2(wlo, whi);
  }
  if (lid < NAC) {
    float tr = expf(ltr[lid]);
    float td = expf(ltd[lid]);
    float a1 = 1.f / td;
    float gg = (td + tr) / (td * tr);
    r1i = expf(-a1 * 0.015625f);
    r2i = expf(-gg * 0.015625f);
    cn1 = expf(-a1 * 0.003125f);
    cn2 = expf(-gg * 0.003125f);
    co1 = expf(-a1 * 0.815625f);
    co2 = expf(-gg * 0.815625f);
    float nrm = 0.f;
    for (int k = 0; k < KF; ++k) {
      float kt = 0.8f - (float)k * 0.015625f;
      float d = expf(-a1 * kt) - expf(-gg * kt);
      nrm = fmaf(d, d, nrm);
    }
    float inorm  = 1.f / sqrtf(nrm);
    float aslope = expf(lass[lid]);
    Adrv2 = aslope * inorm * LOG2E;
    Boff2 = aslope * asoff[lid] * LOG2E;
#pragma unroll
    for (int j = 0; j < 8; ++j) {
      int src = (c16 - delta * j) & 15;
      float ulo = 0.f, uhi = 0.f;
      if (src < NBC)       ulo = expf(lbaw[lid * NBC + src]);
      if ((src ^ 8) < NBC) uhi = expf(lbaw[lid * NBC + (src ^ 8)]);
      wup[j] = pk2(ulo, uhi);
    }
  }

  // ---- output pointers (flat concat: y_bcn, fb, ac_out, y_lnr) ----
  float* yb  = out;
  float* fbp = out + (size_t)BB * TT * NBC;
  float* acp = out + 2 * (size_t)BB * TT * NBC;
  float* ylp = out + 2 * (size_t)BB * TT * NBC + (size_t)BB * TT * NAC;

  __syncthreads();

  // ---- sequential recurrence ----
  int ri = 0;  // ring slot: holds u[s-52] before write, receives u[s]
  for (int s = 0; s < NT; ++s) {
    // prefetch (off critical path)
    float uold = 0.f, xfv = 0.f;
    if (lid < NAC) uold = __half2float(u_ring[ri * RW + lid]);
    if (c16 < NBC) xfv  = __half2float(xf_lds[c16 * XPAD + s]);

    // AC sigmoid (unmasked; lanes>=45 give ac=0.5 against zero weights)
    float mz = fmaf(-Adrv2, S1 - S2, Boff2);
    float ac = __fdividef(1.f, 1.f + exp2_f(mz));

    // fb: pack (ac, ac^8) -> 7 packed rotations + 8 fdot2
    v2h acpk = pk2(ac, rotf<8>(ac));
    float f0 = fdot2f(wfbp[0], acpk,           0.f);
    float f1 = fdot2f(wfbp[1], rotpk<1>(acpk), 0.f);
    f0 = fdot2f(wfbp[2], rotpk<2>(acpk), f0);
    f1 = fdot2f(wfbp[3], rotpk<3>(acpk), f1);
    f0 = fdot2f(wfbp[4], rotpk<4>(acpk), f0);
    f1 = fdot2f(wfbp[5], rotpk<5>(acpk), f1);
    f0 = fdot2f(wfbp[6], rotpk<6>(acpk), f0);
    f1 = fdot2f(wfbp[7], rotpk<7>(acpk), f1);
    const float fbv = xsum32(xsum16(f0 + f1));

    // BC phase (unmasked math; lanes c16>=14 produce harmless garbage)
    float mpz = fmaf(-slope2, xfv + fbv, soff2);
    float prob = __fdividef(1.f, 1.f + exp2_f(mpz));
    float pool2 = fmaf(1.f - RHO, pool_b, RHO);
    float rel = prob * pool2;
    pool_b = pool2 - rel;

    float mlz = fmaf(-slope2, xfv, soff2);
    float pl = __fdividef(1.f, 1.f + exp2_f(mlz));
    float pool2l = fmaf(1.f - RHO, pool_l, RHO);
    float rll = pl * pool2l;
    pool_l = pool2l - rll;

    if (lid < NBC) {                 // row 0 stages outputs
      int st = (s & 3) * NBC + lid;
      yb_st[st] = osc_c * rel;
      fb_st[st] = fbv;
      yl_st[st] = osc_c * rll;
    }

    // u: pack (rel, rel^8) -> 7 packed rotations + 8 fdot2
    v2h relpk = pk2(rel, rotf<8>(rel));
    float u0 = fdot2f(wup[0], relpk,           0.f);
    float u1 = fdot2f(wup[1], rotpk<1>(relpk), 0.f);
    u0 = fdot2f(wup[2], rotpk<2>(relpk), u0);
    u1 = fdot2f(wup[3], rotpk<3>(relpk), u1);
    u0 = fdot2f(wup[4], rotpk<4>(relpk), u0);
    u1 = fdot2f(wup[5], rotpk<5>(relpk), u1);
    u0 = fdot2f(wup[6], rotpk<6>(relpk), u0);
    u1 = fdot2f(wup[7], rotpk<7>(relpk), u1);
    float u = u0 + u1;

    // tail: stage ac, push u into ring, exponential-state update
    if (lid < NAC) {
      ac_st[(s & 3) * NAC + lid] = ac;
      u_ring[ri * RW + lid] = __float2half(u);
      S1 = fmaf(S1, r1i, fmaf(cn1, u, -co1 * uold));
      S2 = fmaf(S2, r2i, fmaf(cn2, u, -co2 * uold));
    }
    ri = (ri + 1 == RING) ? 0 : ri + 1;

    // flush staged outputs every 4 steps (coalesced, off critical path)
    if ((s & 3) == 3 && (s - 3) >= warm) {
      asm volatile("" ::: "memory");
      int tg = t_begin + s - 3;
      size_t ob14 = ((size_t)b * TT + tg) * NBC;
      size_t oa45 = ((size_t)b * TT + tg) * NAC;
      if (lid < 4 * NBC) {
        yb[ob14 + lid]  = yb_st[lid];
        fbp[ob14 + lid] = fb_st[lid];
        ylp[ob14 + lid] = yl_st[lid];
      }
#pragma unroll
      for (int i = 0; i < 3; ++i) {
        int idx = lid + (i << 6);
        if (idx < 4 * NAC) acp[oa45 + idx] = ac_st[idx];
      }
      asm volatile("" ::: "memory");
    }
  }
}

extern "C" void kernel_launch(void* const* d_in, const int* in_sizes, int n_in,
                              void* d_out, int out_size, void* d_ws, size_t ws_size,
                              hipStream_t stream) {
  (void)in_sizes; (void)n_in; (void)d_ws; (void)ws_size; (void)out_size;
  bcn_kernel<<<dim3(BB * NCHUNK), dim3(64), 0, stream>>>(
      (const float*)d_in[0],  // x
      (const float*)d_in[1],  // bc_kernels
      (const float*)d_in[2],  // log_sigmoid_slope
      (const float*)d_in[3],  // sigmoid_offset
      (const float*)d_in[4],  // log_bc_ac_weight
      (const float*)d_in[5],  // log_ac_tau_rise
      (const float*)d_in[6],  // log_ac_tau_decay
      (const float*)d_in[7],  // log_ac_sigmoid_slope
      (const float*)d_in[8],  // ac_sigmoid_offset
      (const float*)d_in[9],  // log_ac_bc_weight
      (const float*)d_in[10], // out_scale
      (float*)d_out);
}

// Round 9
// 130.328 us; speedup vs baseline: 1.3390x; 1.3390x over previous
//
#include <hip/hip_runtime.h>
#include <hip/hip_fp16.h>

#define NBC 14
#define NAC 45
#define KF  52
#define RHO 0.05f
#define TT  4096
#define BB  64
#define CH  128          // output steps per chunk
#define WU  72           // warmup steps (window refill=52 + pool contraction margin)
#define NCHUNK 32        // TT / CH
#define NTMAX (CH + WU)  // 200
#define XPAD  204        // xf row stride in halfs (mult of 4 -> 8B-aligned b64 reads)
#define RING  52
#define LOG2E 1.44269504f

typedef __fp16 v2h __attribute__((ext_vector_type(2)));

template<int J>
__device__ __forceinline__ int rot_i(int v) {
  return __builtin_amdgcn_update_dpp(0, v, 0x120 + J, 0xF, 0xF, true);
}
template<int J>
__device__ __forceinline__ float rotf(float v) {
  return __int_as_float(rot_i<J>(__float_as_int(v)));
}
template<int J>
__device__ __forceinline__ v2h rotpk(v2h v) {
  return __builtin_bit_cast(v2h, rot_i<J>(__builtin_bit_cast(int, v)));
}
template<int J>
__device__ __forceinline__ float swzf(float v) {
  return __int_as_float(__builtin_amdgcn_ds_swizzle(__float_as_int(v), (J << 10) | 0x1f));
}
__device__ __forceinline__ float xsum16(float v) {
#if __has_builtin(__builtin_amdgcn_permlane16_swap)
  typedef int i2 __attribute__((ext_vector_type(2)));
  i2 r = __builtin_amdgcn_permlane16_swap(__float_as_int(v), __float_as_int(v), false, false);
  return __int_as_float(r[0]) + __int_as_float(r[1]);
#else
  return v + swzf<16>(v);
#endif
}
__device__ __forceinline__ float xsum32(float v) {
#if __has_builtin(__builtin_amdgcn_permlane32_swap)
  typedef int i2 __attribute__((ext_vector_type(2)));
  i2 r = __builtin_amdgcn_permlane32_swap(__float_as_int(v), __float_as_int(v), false, false);
  return __int_as_float(r[0]) + __int_as_float(r[1]);
#else
  return v + __shfl_xor(v, 32);
#endif
}
__device__ __forceinline__ v2h pk2(float lo, float hi) {
#if __has_builtin(__builtin_amdgcn_cvt_pkrtz)
  return __builtin_bit_cast(v2h, __builtin_amdgcn_cvt_pkrtz(lo, hi));
#else
  v2h r; r[0] = (__fp16)lo; r[1] = (__fp16)hi; return r;
#endif
}
__device__ __forceinline__ float fdot2f(v2h a, v2h b, float c) {
#if __has_builtin(__builtin_amdgcn_fdot2)
  return __builtin_amdgcn_fdot2(a, b, c, false);
#else
  return fmaf((float)a[0], (float)b[0], fmaf((float)a[1], (float)b[1], c));
#endif
}
__device__ __forceinline__ float exp2_f(float x) {
#if __has_builtin(__builtin_amdgcn_exp2f)
  return __builtin_amdgcn_exp2f(x);
#else
  return exp2f(x);
#endif
}

// LDS pool layout (bytes):
//  [0, 5712)        xf fp16 [NBC][XPAD]                (14*204*2 = 5712)
//  [5712, 10392)    u ring fp16 TRANSPOSED [NAC][RING] (45*52*2 = 4680)
//                   (overlaid by x slice during conv: 251 floats = 1004 B)
//  [10392, 11832)   ac staging  [8][NAC] f32
//  [11832, 13176)   yb/fb/yl staging [8][NBC] f32 x3
#define POOL_BYTES 13184

__global__ __launch_bounds__(64)
void bcn_kernel(const float* __restrict__ x,
                const float* __restrict__ bck,
                const float* __restrict__ lss,
                const float* __restrict__ soff,
                const float* __restrict__ lbaw,
                const float* __restrict__ ltr,
                const float* __restrict__ ltd,
                const float* __restrict__ lass,
                const float* __restrict__ asoff,
                const float* __restrict__ labw,
                const float* __restrict__ oscale,
                float* __restrict__ out)
{
  __shared__ __align__(16) char pool[POOL_BYTES];
  __half* xf_lds  = (__half*)pool;                   // [NBC][XPAD]
  __half* u_ringT = (__half*)(pool + 5712);          // [NAC][RING] transposed
  float*  x_lds   = (float*)(pool + 5712);           // overlay during conv
  float*  ac_st   = (float*)(pool + 10392);          // [8][NAC]
  float*  yb_st   = (float*)(pool + 11832);          // [8][NBC]
  float*  fb_st   = yb_st + 8 * NBC;
  float*  yl_st   = fb_st + 8 * NBC;

  const int lid   = threadIdx.x;
  const int c16   = lid & 15;
  const int q     = lid >> 4;
  const int blk   = blockIdx.x;
  const int b     = blk >> 5;          // batch (NCHUNK=32)
  const int chunk = blk & 31;
  const int t0      = chunk * CH;
  const int warm    = (chunk == 0) ? 0 : WU;
  const int t_begin = t0 - warm;
  const int NT      = CH + warm;       // 128 (chunk 0) or 200; multiple of 8

  // DPP row_ror direction probe: srcl(j) = (c16 - delta*j) & 15
  const int probe = __builtin_amdgcn_update_dpp(0, c16, 0x121, 0xF, 0xF, true);
  const int delta = (c16 - probe) & 15;

  // ---- load stimulus slice into overlay (causal zero pad at t<0) ----
  for (int p = lid; p < NT + KF - 1; p += 64) {
    int gt = t_begin - (KF - 1) + p;
    x_lds[p] = (gt >= 0) ? x[b * TT + gt] : 0.f;
  }
  __syncthreads();

  // ---- causal conv into xf_lds (fp16) ----
  for (int ib = 0; ib < ((NT + 63) >> 6); ++ib) {
    int tau = lid + (ib << 6);
    if (tau < NT) {
      float acc[NBC];
#pragma unroll
      for (int c = 0; c < NBC; ++c) acc[c] = 0.f;
#pragma unroll 4
      for (int k = 0; k < KF; ++k) {
        float xv = x_lds[tau + k];
#pragma unroll
        for (int c = 0; c < NBC; ++c) acc[c] = fmaf(bck[c * KF + k], xv, acc[c]);
      }
#pragma unroll
      for (int c = 0; c < NBC; ++c) xf_lds[c * XPAD + tau] = __float2half(acc[c]);
    }
  }
  __syncthreads();

  // ---- zero u ring (x overlay is dead now) ----
  for (int i = lid; i < (NAC * RING) / 2; i += 64) ((unsigned int*)u_ringT)[i] = 0u;

  // ---- per-lane parameters ----
  float slope2 = 0.f, soff2 = 0.f, osc_c = 0.f;
  float pool_b = 1.f, pool_l = 1.f;
  float r1i = 0.f, r2i = 0.f, co1 = 0.f, co2 = 0.f, cn1 = 0.f, cn2 = 0.f;
  float Adrv2 = 0.f, Boff2 = 0.f;
  v2h wfbp[8];
  v2h wup[8];
  float S1 = 0.f, S2 = 0.f;

#pragma unroll
  for (int j = 0; j < 8; ++j) { wfbp[j] = pk2(0.f, 0.f); wup[j] = pk2(0.f, 0.f); }

  if (c16 < NBC) {
    float sl = expf(lss[c16]);
    slope2 = sl * LOG2E;
    soff2  = soff[c16] * sl * LOG2E;
    osc_c  = oscale[c16];
  }
#pragma unroll
  for (int j = 0; j < 8; ++j) {
    int src = (c16 - delta * j) & 15;
    float wlo = 0.f, whi = 0.f;
    if (c16 < NBC) {
      int a0 = 16 * q + src;
      int a1 = 16 * q + (src ^ 8);
      if (a0 < NAC) wlo = -expf(labw[c16 * NAC + a0]);
      if (a1 < NAC) whi = -expf(labw[c16 * NAC + a1]);
    }
    wfbp[j] = pk2(wlo, whi);
  }
  if (lid < NAC) {
    float tr = expf(ltr[lid]);
    float td = expf(ltd[lid]);
    float a1 = 1.f / td;
    float gg = (td + tr) / (td * tr);
    r1i = expf(-a1 * 0.015625f);
    r2i = expf(-gg * 0.015625f);
    cn1 = expf(-a1 * 0.003125f);
    cn2 = expf(-gg * 0.003125f);
    co1 = expf(-a1 * 0.815625f);
    co2 = expf(-gg * 0.815625f);
    float nrm = 0.f;
    for (int k = 0; k < KF; ++k) {
      float kt = 0.8f - (float)k * 0.015625f;
      float d = expf(-a1 * kt) - expf(-gg * kt);
      nrm = fmaf(d, d, nrm);
    }
    float inorm  = 1.f / sqrtf(nrm);
    float aslope = expf(lass[lid]);
    Adrv2 = aslope * inorm * LOG2E;
    Boff2 = aslope * asoff[lid] * LOG2E;
#pragma unroll
    for (int j = 0; j < 8; ++j) {
      int src = (c16 - delta * j) & 15;
      float ulo = 0.f, uhi = 0.f;
      if (src < NBC)       ulo = expf(lbaw[lid * NBC + src]);
      if ((src ^ 8) < NBC) uhi = expf(lbaw[lid * NBC + (src ^ 8)]);
      wup[j] = pk2(ulo, uhi);
    }
  }

  float* yb  = out;
  float* fbp = out + (size_t)BB * TT * NBC;
  float* acp = out + 2 * (size_t)BB * TT * NBC;
  float* ylp = out + 2 * (size_t)BB * TT * NBC + (size_t)BB * TT * NAC;

  __syncthreads();

  // one recurrence step (J static via always_inline + constant args)
  auto step = [&](int s, int slot, float xfv, float uold) __attribute__((always_inline)) {
    // AC sigmoid (unmasked; lanes>=45 give ac=0.5 against zero weights)
    float mz = fmaf(-Adrv2, S1 - S2, Boff2);
    float ac = __fdividef(1.f, 1.f + exp2_f(mz));

    // fb: pack (ac, ac^8) -> 7 packed rotations + 8 fdot2 + VALU butterflies
    v2h acpk = pk2(ac, rotf<8>(ac));
    float f0 = fdot2f(wfbp[0], acpk,           0.f);
    float f1 = fdot2f(wfbp[1], rotpk<1>(acpk), 0.f);
    f0 = fdot2f(wfbp[2], rotpk<2>(acpk), f0);
    f1 = fdot2f(wfbp[3], rotpk<3>(acpk), f1);
    f0 = fdot2f(wfbp[4], rotpk<4>(acpk), f0);
    f1 = fdot2f(wfbp[5], rotpk<5>(acpk), f1);
    f0 = fdot2f(wfbp[6], rotpk<6>(acpk), f0);
    f1 = fdot2f(wfbp[7], rotpk<7>(acpk), f1);
    const float fbv = xsum32(xsum16(f0 + f1));

    // BC phase (unmasked math; garbage lanes meet zero weights downstream)
    float mpz = fmaf(-slope2, xfv + fbv, soff2);
    float prob = __fdividef(1.f, 1.f + exp2_f(mpz));
    float pool2 = fmaf(1.f - RHO, pool_b, RHO);
    float rel = prob * pool2;
    pool_b = pool2 - rel;

    float mlz = fmaf(-slope2, xfv, soff2);
    float pl = __fdividef(1.f, 1.f + exp2_f(mlz));
    float pool2l = fmaf(1.f - RHO, pool_l, RHO);
    float rll = pl * pool2l;
    pool_l = pool2l - rll;

    if (lid < NBC) {
      int st = (s & 7) * NBC + lid;
      yb_st[st] = osc_c * rel;
      fb_st[st] = fbv;
      yl_st[st] = osc_c * rll;
    }

    // u: pack (rel, rel^8) -> 7 packed rotations + 8 fdot2
    v2h relpk = pk2(rel, rotf<8>(rel));
    float u0 = fdot2f(wup[0], relpk,           0.f);
    float u1 = fdot2f(wup[1], rotpk<1>(relpk), 0.f);
    u0 = fdot2f(wup[2], rotpk<2>(relpk), u0);
    u1 = fdot2f(wup[3], rotpk<3>(relpk), u1);
    u0 = fdot2f(wup[4], rotpk<4>(relpk), u0);
    u1 = fdot2f(wup[5], rotpk<5>(relpk), u1);
    u0 = fdot2f(wup[6], rotpk<6>(relpk), u0);
    u1 = fdot2f(wup[7], rotpk<7>(relpk), u1);
    float u = u0 + u1;

    if (lid < NAC) {
      ac_st[(s & 7) * NAC + lid] = ac;
      u_ringT[lid * RING + slot] = __float2half(u);
      S1 = fmaf(S1, r1i, fmaf(cn1, u, -co1 * uold));
      S2 = fmaf(S2, r2i, fmaf(cn2, u, -co2 * uold));
    }
  };

  int r4 = 0;  // ring base slot, multiple of 4; slots r4..r4+3 hold u[s-52..s-49]
  for (int s4 = 0; s4 < NT; s4 += 4) {
    // batched on-chain DS reads: 4 steps of xf and uold in one b64 each
    uint2 xr = *(const uint2*)&xf_lds[c16 * XPAD + s4];        // safe in-pool for c16>=14
    uint2 ur = *(const uint2*)&u_ringT[lid * RING + r4];       // safe in-pool for lid>=45
    v2h x01 = __builtin_bit_cast(v2h, xr.x);
    v2h x23 = __builtin_bit_cast(v2h, xr.y);
    v2h uo01 = __builtin_bit_cast(v2h, ur.x);
    v2h uo23 = __builtin_bit_cast(v2h, ur.y);

    step(s4 + 0, r4 + 0, (float)x01[0], (float)uo01[0]);
    step(s4 + 1, r4 + 1, (float)x01[1], (float)uo01[1]);
    step(s4 + 2, r4 + 2, (float)x23[0], (float)uo23[0]);
    step(s4 + 3, r4 + 3, (float)x23[1], (float)uo23[1]);

    r4 += 4; if (r4 == RING) r4 = 0;

    // flush staged outputs every 8 steps (coalesced, off critical path)
    int s = s4 + 3;
    if ((s & 7) == 7 && (s - 7) >= warm) {
      asm volatile("" ::: "memory");
      int tg = t_begin + s - 7;
      size_t ob14 = ((size_t)b * TT + tg) * NBC;
      size_t oa45 = ((size_t)b * TT + tg) * NAC;
#pragma unroll
      for (int i = 0; i < 2; ++i) {
        int idx = lid + (i << 6);
        if (idx < 8 * NBC) {
          yb[ob14 + idx]  = yb_st[idx];
          fbp[ob14 + idx] = fb_st[idx];
          ylp[ob14 + idx] = yl_st[idx];
        }
      }
#pragma unroll
      for (int i = 0; i < 6; ++i) {
        int idx = lid + (i << 6);
        if (idx < 8 * NAC) acp[oa45 + idx] = ac_st[idx];
      }
      asm volatile("" ::: "memory");
    }
  }
}

extern "C" void kernel_launch(void* const* d_in, const int* in_sizes, int n_in,
                              void* d_out, int out_size, void* d_ws, size_t ws_size,
                              hipStream_t stream) {
  (void)in_sizes; (void)n_in; (void)d_ws; (void)ws_size; (void)out_size;
  bcn_kernel<<<dim3(BB * NCHUNK), dim3(64), 0, stream>>>(
      (const float*)d_in[0],  // x
      (const float*)d_in[1],  // bc_kernels
      (const float*)d_in[2],  // log_sigmoid_slope
      (const float*)d_in[3],  // sigmoid_offset
      (const float*)d_in[4],  // log_bc_ac_weight
      (const float*)d_in[5],  // log_ac_tau_rise
      (const float*)d_in[6],  // log_ac_tau_decay
      (const float*)d_in[7],  // log_ac_sigmoid_slope
      (const float*)d_in[8],  // ac_sigmoid_offset
      (const float*)d_in[9],  // log_ac_bc_weight
      (const float*)d_in[10], // out_scale
      (float*)d_out);
}

// Round 10
// 126.911 us; speedup vs baseline: 1.3751x; 1.0269x over previous
//
#include <hip/hip_runtime.h>
#include <hip/hip_fp16.h>

#define NBC 14
#define NAC 45
#define KF  52
#define RHO 0.05f
#define TT  4096
#define BB  64
#define CH  128          // output steps per chunk
#define WU  72           // warmup steps (u-window exact after 52; pool decay margin)
#define NCHUNK 32        // TT / CH
#define NTMAX (CH + WU)  // 200
#define XPAD  204        // xf row stride in halfs
#define RING  52
#define LOG2E 1.44269504f

typedef __fp16 v2h __attribute__((ext_vector_type(2)));
typedef float  f2  __attribute__((ext_vector_type(2)));

template<int J>
__device__ __forceinline__ float swzf(float v) {
  return __int_as_float(__builtin_amdgcn_ds_swizzle(__float_as_int(v), (J << 10) | 0x1f));
}
__device__ __forceinline__ float xsum16(float v) {
#if __has_builtin(__builtin_amdgcn_permlane16_swap)
  typedef int i2 __attribute__((ext_vector_type(2)));
  i2 r = __builtin_amdgcn_permlane16_swap(__float_as_int(v), __float_as_int(v), false, false);
  return __int_as_float(r[0]) + __int_as_float(r[1]);
#else
  return v + swzf<16>(v);
#endif
}
__device__ __forceinline__ float xsum32(float v) {
#if __has_builtin(__builtin_amdgcn_permlane32_swap)
  typedef int i2 __attribute__((ext_vector_type(2)));
  i2 r = __builtin_amdgcn_permlane32_swap(__float_as_int(v), __float_as_int(v), false, false);
  return __int_as_float(r[0]) + __int_as_float(r[1]);
#else
  return v + __shfl_xor(v, 32);
#endif
}
__device__ __forceinline__ v2h pk2(float lo, float hi) {
#if __has_builtin(__builtin_amdgcn_cvt_pkrtz)
  return __builtin_bit_cast(v2h, __builtin_amdgcn_cvt_pkrtz(lo, hi));
#else
  v2h r; r[0] = (__fp16)lo; r[1] = (__fp16)hi; return r;
#endif
}
__device__ __forceinline__ v2h bch(unsigned u) { return __builtin_bit_cast(v2h, u); }
__device__ __forceinline__ float fdot2f(v2h a, v2h b, float c) {
#if __has_builtin(__builtin_amdgcn_fdot2)
  return __builtin_amdgcn_fdot2(a, b, c, false);
#else
  return fmaf((float)a[0], (float)b[0], fmaf((float)a[1], (float)b[1], c));
#endif
}
__device__ __forceinline__ float exp2_f(float x) {
#if __has_builtin(__builtin_amdgcn_exp2f)
  return __builtin_amdgcn_exp2f(x);
#else
  return exp2f(x);
#endif
}

// LDS pool (bytes):
//  [0,     5712)  xf fp16 [NBC][XPAD]
//  [5712, 10392)  u ring fp16 [NAC][RING]  (x-slice overlay during conv)
//  [10400,11168)  ac ring fp16 [8][48]     (gather source + output staging)
//  [11168,11200)  rel fp16 [16]
//  [11200,11648)  yb_st f32 [8][14]
//  [11648,12096)  fb_st f32 [8][14]
//  [12096,12544)  yl_st f32 [8][14]
#define POOL_BYTES 12544

__global__ __launch_bounds__(64)
void bcn_kernel(const float* __restrict__ x,
                const float* __restrict__ bck,
                const float* __restrict__ lss,
                const float* __restrict__ soff,
                const float* __restrict__ lbaw,
                const float* __restrict__ ltr,
                const float* __restrict__ ltd,
                const float* __restrict__ lass,
                const float* __restrict__ asoff,
                const float* __restrict__ labw,
                const float* __restrict__ oscale,
                float* __restrict__ out)
{
  __shared__ __align__(16) char pool[POOL_BYTES];
  __half* xf_lds  = (__half*)pool;                   // [NBC][XPAD]
  __half* u_ringT = (__half*)(pool + 5712);          // [NAC][RING]
  float*  x_lds   = (float*)(pool + 5712);           // overlay during conv
  __half* acr     = (__half*)(pool + 10400);         // [8][48]
  __half* relr    = (__half*)(pool + 11168);         // [16]
  float*  yb_st   = (float*)(pool + 11200);          // [8][NBC]
  float*  fb_st   = (float*)(pool + 11648);
  float*  yl_st   = (float*)(pool + 12096);

  const int lid   = threadIdx.x;
  const int c16   = lid & 15;
  const int q     = lid >> 4;
  const int blk   = blockIdx.x;
  const int b     = blk >> 5;          // batch (NCHUNK=32)
  const int chunk = blk & 31;
  const int t0      = chunk * CH;
  const int warm    = (chunk == 0) ? 0 : WU;
  const int t_begin = t0 - warm;
  const int NT      = CH + warm;       // 128 or 200 (both mult of 8)

  // ---- load stimulus slice into overlay (causal zero pad at t<0) ----
  for (int p = lid; p < NT + KF - 1; p += 64) {
    int gt = t_begin - (KF - 1) + p;
    x_lds[p] = (gt >= 0) ? x[b * TT + gt] : 0.f;
  }
  __syncthreads();

  // ---- causal conv into xf_lds (fp16) ----
  for (int ib = 0; ib < ((NT + 63) >> 6); ++ib) {
    int tau = lid + (ib << 6);
    if (tau < NT) {
      float acc[NBC];
#pragma unroll
      for (int c = 0; c < NBC; ++c) acc[c] = 0.f;
#pragma unroll 4
      for (int k = 0; k < KF; ++k) {
        float xv = x_lds[tau + k];
#pragma unroll
        for (int c = 0; c < NBC; ++c) acc[c] = fmaf(bck[c * KF + k], xv, acc[c]);
      }
#pragma unroll
      for (int c = 0; c < NBC; ++c) xf_lds[c * XPAD + tau] = __float2half(acc[c]);
    }
  }
  __syncthreads();

  // ---- zero u ring + ac ring + relr (x overlay dead now) ----
  for (int i = lid; i < (11200 - 5712) / 4; i += 64) ((unsigned int*)(pool + 5712))[i] = 0u;

  // ---- per-lane parameters ----
  float slope2 = 0.f, soff2 = 0.f, osc_c = 0.f;
  f2 poolv; poolv.x = 1.f; poolv.y = 1.f;           // (BCN pool, LNR pool)
  f2 S;     S.x = 0.f;     S.y = 0.f;               // (S1, S2)
  f2 rv, cn, co;  rv.x = rv.y = cn.x = cn.y = co.x = co.y = 0.f;
  float Adrv2 = 0.f, Boff2 = 0.f;
  v2h wfbp[8];   // fb weights: j -> (-w2[c16][16q+2j], -w2[c16][16q+2j+1])
  v2h wup[7];    // u  weights: j -> (w1[lid][2j], w1[lid][2j+1])

#pragma unroll
  for (int j = 0; j < 8; ++j) wfbp[j] = pk2(0.f, 0.f);
#pragma unroll
  for (int j = 0; j < 7; ++j) wup[j] = pk2(0.f, 0.f);

  if (c16 < NBC) {
    float sl = expf(lss[c16]);
    slope2 = sl * LOG2E;
    soff2  = soff[c16] * sl * LOG2E;
    osc_c  = oscale[c16];
#pragma unroll
    for (int j = 0; j < 8; ++j) {
      int a0 = 16 * q + 2 * j;
      float wlo = (a0     < NAC) ? -expf(labw[c16 * NAC + a0])     : 0.f;
      float whi = (a0 + 1 < NAC) ? -expf(labw[c16 * NAC + a0 + 1]) : 0.f;
      wfbp[j] = pk2(wlo, whi);
    }
  }
  if (lid < NAC) {
    float tr = expf(ltr[lid]);
    float td = expf(ltd[lid]);
    float a1 = 1.f / td;
    float gg = (td + tr) / (td * tr);
    rv.x = expf(-a1 * 0.015625f);  rv.y = expf(-gg * 0.015625f);
    cn.x = expf(-a1 * 0.003125f);  cn.y = expf(-gg * 0.003125f);
    co.x = expf(-a1 * 0.815625f);  co.y = expf(-gg * 0.815625f);
    float nrm = 0.f;
    for (int k = 0; k < KF; ++k) {
      float kt = 0.8f - (float)k * 0.015625f;
      float d = expf(-a1 * kt) - expf(-gg * kt);
      nrm = fmaf(d, d, nrm);
    }
    float inorm  = 1.f / sqrtf(nrm);
    float aslope = expf(lass[lid]);
    Adrv2 = aslope * inorm * LOG2E;
    Boff2 = aslope * asoff[lid] * LOG2E;
#pragma unroll
    for (int j = 0; j < 7; ++j)
      wup[j] = pk2(expf(lbaw[lid * NBC + 2 * j]), expf(lbaw[lid * NBC + 2 * j + 1]));
  }

  float* yb  = out;
  float* fbp = out + (size_t)BB * TT * NBC;
  float* acp = out + 2 * (size_t)BB * TT * NBC;
  float* ylp = out + 2 * (size_t)BB * TT * NBC + (size_t)BB * TT * NAC;

  __syncthreads();

  // one recurrence step; all cross-lane traffic via tiny LDS broadcast buffers
  auto step = [&](int s, int slot, float xfv, float uold, bool emit)
      __attribute__((always_inline)) {
    // AC sigmoid (unmasked; lanes>=45 produce garbage that meets zero weights)
    float mz = fmaf(-Adrv2, S.x - S.y, Boff2);
    float ac = __fdividef(1.f, 1.f + exp2_f(mz));
    if (lid < NAC) acr[(s & 7) * 48 + lid] = __float2half(ac);

    // fb[c16] partial over own row's 16 ACs: 2 broadcast b128 reads + 8 fdot2
    const uint4* ab = (const uint4*)(acr + (s & 7) * 48 + (q << 4));
    uint4 a0 = ab[0], a1 = ab[1];
    float f0 = fdot2f(wfbp[0], bch(a0.x), 0.f);
    float f1 = fdot2f(wfbp[1], bch(a0.y), 0.f);
    f0 = fdot2f(wfbp[2], bch(a0.z), f0);
    f1 = fdot2f(wfbp[3], bch(a0.w), f1);
    f0 = fdot2f(wfbp[4], bch(a1.x), f0);
    f1 = fdot2f(wfbp[5], bch(a1.y), f1);
    f0 = fdot2f(wfbp[6], bch(a1.z), f0);
    f1 = fdot2f(wfbp[7], bch(a1.w), f1);
    const float fbv = xsum32(xsum16(f0 + f1));   // sum partials across 4 rows

    // BC + LNR sigmoids (shared pre-add), pool pair packed f32x2
    float mlz = fmaf(-slope2, xfv, soff2);
    float mpz = fmaf(-slope2, fbv, mlz);
    f2 pv; pv.x = __fdividef(1.f, 1.f + exp2_f(mpz));
           pv.y = __fdividef(1.f, 1.f + exp2_f(mlz));
    f2 pool2 = poolv * (1.f - RHO) + RHO;
    f2 relv  = pv * pool2;
    poolv = pool2 - relv;
    float rel = relv.x;
    if (lid < NBC) relr[lid] = __float2half(rel);
    if (emit && lid < NBC) {
      int st = (s & 7) * NBC + lid;
      f2 yv = relv * osc_c;
      yb_st[st] = yv.x;
      fb_st[st] = fbv;
      yl_st[st] = yv.y;
    }

    // u[lid] = sum_c w1[lid][c]*rel[c]: 2 broadcast b128 reads + 7 fdot2
    const uint4* rb = (const uint4*)relr;
    uint4 r0 = rb[0], r1 = rb[1];
    float u0 = fdot2f(wup[0], bch(r0.x), 0.f);
    float u1 = fdot2f(wup[1], bch(r0.y), 0.f);
    u0 = fdot2f(wup[2], bch(r0.z), u0);
    u1 = fdot2f(wup[3], bch(r0.w), u1);
    u0 = fdot2f(wup[4], bch(r1.x), u0);
    u1 = fdot2f(wup[5], bch(r1.y), u1);
    u0 = fdot2f(wup[6], bch(r1.z), u0);
    float u = u0 + u1;

    if (lid < NAC) {
      u_ringT[lid * RING + slot] = __float2half(u);
      f2 uu; uu.x = u;    uu.y = u;
      f2 uo; uo.x = uold; uo.y = uold;
      S = S * rv + (cn * uu - co * uo);     // packed: S1,S2 update
    }
  };

  int r4 = 0;  // ring base slot (mult of 4); slots r4..r4+3 hold u[s-52..s-49]
  for (int s4 = 0; s4 < NT; s4 += 4) {
    // batched on-chain DS reads: 4 steps of xf and uold in one b64 each
    uint2 xr = *(const uint2*)&xf_lds[c16 * XPAD + s4];
    uint2 ur = *(const uint2*)&u_ringT[lid * RING + r4];
    v2h x01 = __builtin_bit_cast(v2h, xr.x);
    v2h x23 = __builtin_bit_cast(v2h, xr.y);
    v2h uo01 = __builtin_bit_cast(v2h, ur.x);
    v2h uo23 = __builtin_bit_cast(v2h, ur.y);

    if (s4 >= warm) {
      step(s4 + 0, r4 + 0, (float)x01[0], (float)uo01[0], true);
      step(s4 + 1, r4 + 1, (float)x01[1], (float)uo01[1], true);
      step(s4 + 2, r4 + 2, (float)x23[0], (float)uo23[0], true);
      step(s4 + 3, r4 + 3, (float)x23[1], (float)uo23[1], true);

      // flush staged outputs every 8 steps (coalesced, off critical path)
      if ((s4 & 7) == 4 && s4 >= warm + 4) {
        asm volatile("" ::: "memory");
        int tg = t_begin + s4 - 4;             // = t_begin + s - 7
        size_t ob14 = ((size_t)b * TT + tg) * NBC;
        size_t oa45 = ((size_t)b * TT + tg) * NAC;
#pragma unroll
        for (int i = 0; i < 2; ++i) {
          int idx = lid + (i << 6);
          if (idx < 8 * NBC) {
            yb[ob14 + idx]  = yb_st[idx];
            fbp[ob14 + idx] = fb_st[idx];
            ylp[ob14 + idx] = yl_st[idx];
          }
        }
        if (lid < NAC) {
#pragma unroll
          for (int sl = 0; sl < 8; ++sl)
            acp[oa45 + sl * NAC + lid] = __half2float(acr[sl * 48 + lid]);
        }
        asm volatile("" ::: "memory");
      }
    } else {
      step(s4 + 0, r4 + 0, (float)x01[0], (float)uo01[0], false);
      step(s4 + 1, r4 + 1, (float)x01[1], (float)uo01[1], false);
      step(s4 + 2, r4 + 2, (float)x23[0], (float)uo23[0], false);
      step(s4 + 3, r4 + 3, (float)x23[1], (float)uo23[1], false);
    }

    r4 += 4; if (r4 == RING) r4 = 0;
  }
}

extern "C" void kernel_launch(void* const* d_in, const int* in_sizes, int n_in,
                              void* d_out, int out_size, void* d_ws, size_t ws_size,
                              hipStream_t stream) {
  (void)in_sizes; (void)n_in; (void)d_ws; (void)ws_size; (void)out_size;
  bcn_kernel<<<dim3(BB * NCHUNK), dim3(64), 0, stream>>>(
      (const float*)d_in[0],  // x
      (const float*)d_in[1],  // bc_kernels
      (const float*)d_in[2],  // log_sigmoid_slope
      (const float*)d_in[3],  // sigmoid_offset
      (const float*)d_in[4],  // log_bc_ac_weight
      (const float*)d_in[5],  // log_ac_tau_rise
      (const float*)d_in[6],  // log_ac_tau_decay
      (const float*)d_in[7],  // log_ac_sigmoid_slope
      (const float*)d_in[8],  // ac_sigmoid_offset
      (const float*)d_in[9],  // log_ac_bc_weight
      (const float*)d_in[10], // out_scale
      (float*)d_out);
}

// Round 11
// 113.890 us; speedup vs baseline: 1.5323x; 1.1143x over previous
//
#include <hip/hip_runtime.h>
#include <hip/hip_fp16.h>

#define NBC 14
#define NAC 45
#define KF  52
#define RHO 0.05f
#define TT  4096
#define BB  64
#define CHC 64           // outputs per chain
#define WU  56           // warmup steps (kernel discounts old taps; pool err ~6e-3 -> y ~2e-4)
#define NPAIR 32         // chunk pairs per batch; block = (batch, pair)
#define NTW (WU + CHC)   // 120 steps per chain
#define SPAN (WU + 2*CHC)// 184: xf range covers both chains
#define XPAD 188         // xf row stride (halfs), mult of 4
#define RING 52
#define LOG2E 1.44269504f

typedef __fp16 v2h __attribute__((ext_vector_type(2)));
typedef float  f2  __attribute__((ext_vector_type(2)));
typedef int    i2v __attribute__((ext_vector_type(2)));

__device__ __forceinline__ v2h bch(unsigned u) { return __builtin_bit_cast(v2h, u); }
__device__ __forceinline__ unsigned bcu(v2h h) { return __builtin_bit_cast(unsigned, h); }
__device__ __forceinline__ v2h pk2(float lo, float hi) {
#if __has_builtin(__builtin_amdgcn_cvt_pkrtz)
  return __builtin_bit_cast(v2h, __builtin_amdgcn_cvt_pkrtz(lo, hi));
#else
  v2h r; r[0] = (__fp16)lo; r[1] = (__fp16)hi; return r;
#endif
}
__device__ __forceinline__ v2h xsum16h(v2h v) {
#if __has_builtin(__builtin_amdgcn_permlane16_swap)
  i2v r = __builtin_amdgcn_permlane16_swap((int)bcu(v), (int)bcu(v), false, false);
  return bch((unsigned)r[0]) + bch((unsigned)r[1]);
#else
  return v + bch((unsigned)__builtin_amdgcn_ds_swizzle((int)bcu(v), (16 << 10) | 0x1f));
#endif
}
__device__ __forceinline__ v2h xsum32h(v2h v) {
#if __has_builtin(__builtin_amdgcn_permlane32_swap)
  i2v r = __builtin_amdgcn_permlane32_swap((int)bcu(v), (int)bcu(v), false, false);
  return bch((unsigned)r[0]) + bch((unsigned)r[1]);
#else
  return v + bch((unsigned)__shfl_xor((int)bcu(v), 32));
#endif
}
__device__ __forceinline__ float exp2_f(float x) {
#if __has_builtin(__builtin_amdgcn_exp2f)
  return __builtin_amdgcn_exp2f(x);
#else
  return exp2f(x);
#endif
}

// LDS pool layout (bytes):
//  [0,     5264)  xf fp16 [NBC][XPAD]
//  [5264, 14624)  u ring u32 [NAC][RING], packed (uA,uB) f16   (x-slice overlay in conv)
//  [14624,15392)  ac gather/staging u32 [4][48], packed (acA,acB) f16
//  [15392,15456)  rel u32 [16], packed (relA,relB) f16
//  [15456,15904)  yb staging f2 [4*NBC]
//  [15904,16352)  fb staging f2
//  [16352,16800)  yl staging f2
#define POOL_BYTES 16800

__global__ __launch_bounds__(64)
void bcn_kernel(const float* __restrict__ x,
                const float* __restrict__ bck,
                const float* __restrict__ lss,
                const float* __restrict__ soff,
                const float* __restrict__ lbaw,
                const float* __restrict__ ltr,
                const float* __restrict__ ltd,
                const float* __restrict__ lass,
                const float* __restrict__ asoff,
                const float* __restrict__ labw,
                const float* __restrict__ oscale,
                float* __restrict__ out)
{
  __shared__ __align__(16) char pool[POOL_BYTES];
  __half*   xf_lds = (__half*)pool;                    // [NBC][XPAD]
  unsigned* u_ring = (unsigned*)(pool + 5264);         // [NAC][RING]
  float*    x_lds  = (float*)(pool + 5264);            // overlay during conv
  unsigned* acr    = (unsigned*)(pool + 14624);        // [4][48]
  unsigned* relr   = (unsigned*)(pool + 15392);        // [16]
  f2*       ybst   = (f2*)(pool + 15456);              // [4*NBC]
  f2*       fbst   = (f2*)(pool + 15904);
  f2*       ylst   = (f2*)(pool + 16352);

  const int lid   = threadIdx.x;
  const int c16   = lid & 15;
  const int q     = lid >> 4;
  const int blk   = blockIdx.x;
  const int b     = blk >> 5;            // batch
  const int p     = blk & 31;            // chunk pair
  const int t0A   = p * (2 * CHC);       // chain A chunk start; B = t0A + 64
  const bool firstA = (p == 0);
  const int t_begin = t0A - WU;

  // ---- load stimulus slice into overlay (causal zero pad at t<0) ----
  for (int i = lid; i < SPAN + KF - 1; i += 64) {
    int gt = t_begin - (KF - 1) + i;
    x_lds[i] = (gt >= 0) ? x[b * TT + gt] : 0.f;
  }
  __syncthreads();

  // ---- causal conv into xf_lds (fp16), serves both chains ----
  for (int ib = 0; ib < 3; ++ib) {
    int tau = lid + (ib << 6);
    if (tau < SPAN) {
      float acc[NBC];
#pragma unroll
      for (int c = 0; c < NBC; ++c) acc[c] = 0.f;
#pragma unroll 4
      for (int k = 0; k < KF; ++k) {
        float xv = x_lds[tau + k];
#pragma unroll
        for (int c = 0; c < NBC; ++c) acc[c] = fmaf(bck[c * KF + k], xv, acc[c]);
      }
#pragma unroll
      for (int c = 0; c < NBC; ++c) xf_lds[c * XPAD + tau] = __float2half(acc[c]);
    }
  }
  __syncthreads();

  // ---- zero ring + acr + relr (x overlay dead now) ----
  for (int i = lid; i < (15456 - 5264) / 4; i += 64) ((unsigned*)(pool + 5264))[i] = 0u;

  // ---- per-lane parameters ----
  float slope2 = 0.f, soff2 = 0.f, osc_c = 0.f;
  f2 poolA; poolA.x = 1.f; poolA.y = 1.f;      // (BCN pool, LNR pool), chain A
  f2 poolB; poolB.x = 1.f; poolB.y = 1.f;
  f2 SA; SA.x = 0.f; SA.y = 0.f;               // (S1,S2) chain A
  f2 SB; SB.x = 0.f; SB.y = 0.f;
  f2 rv2, cn2, co2; rv2.x = rv2.y = cn2.x = cn2.y = co2.x = co2.y = 0.f;
  float Adrv2 = 0.f, Boff2 = 0.f;
  v2h wfbh[16];  // fb weights (w,w): j -> -exp(labw[c16][16q+j])
  v2h wuh[NBC];  // u  weights (w,w): c -> exp(lbaw[lid][c])

#pragma unroll
  for (int j = 0; j < 16; ++j) wfbh[j] = pk2(0.f, 0.f);
#pragma unroll
  for (int c = 0; c < NBC; ++c) wuh[c] = pk2(0.f, 0.f);

  if (c16 < NBC) {
    float sl = expf(lss[c16]);
    slope2 = sl * LOG2E;
    soff2  = soff[c16] * sl * LOG2E;
    osc_c  = oscale[c16];
#pragma unroll
    for (int j = 0; j < 16; ++j) {
      int a = 16 * q + j;
      if (a < NAC) { float w = -expf(labw[c16 * NAC + a]); wfbh[j] = pk2(w, w); }
    }
  }
  if (lid < NAC) {
    float tr = expf(ltr[lid]);
    float td = expf(ltd[lid]);
    float a1 = 1.f / td;
    float gg = (td + tr) / (td * tr);
    rv2.x = expf(-a1 * 0.015625f);  rv2.y = expf(-gg * 0.015625f);
    cn2.x = expf(-a1 * 0.003125f);  cn2.y = expf(-gg * 0.003125f);
    co2.x = expf(-a1 * 0.815625f);  co2.y = expf(-gg * 0.815625f);
    float nrm = 0.f;
    for (int k = 0; k < KF; ++k) {
      float kt = 0.8f - (float)k * 0.015625f;
      float d = expf(-a1 * kt) - expf(-gg * kt);
      nrm = fmaf(d, d, nrm);
    }
    float inorm  = 1.f / sqrtf(nrm);
    float aslope = expf(lass[lid]);
    Adrv2 = aslope * inorm * LOG2E;
    Boff2 = aslope * asoff[lid] * LOG2E;
#pragma unroll
    for (int c = 0; c < NBC; ++c) {
      float w = expf(lbaw[lid * NBC + c]);
      wuh[c] = pk2(w, w);
    }
  }

  float* yb  = out;
  float* fbp = out + (size_t)BB * TT * NBC;
  float* acp = out + 2 * (size_t)BB * TT * NBC;
  float* ylp = out + 2 * (size_t)BB * TT * NBC + (size_t)BB * TT * NAC;

  __syncthreads();

  // ---- one dual-chain recurrence step ----
  auto step = [&](int slot4, int rslot, float xfA, float xfB, float uoA, float uoB,
                  bool emit) __attribute__((always_inline)) {
    // AC sigmoids (both chains; lanes>=45 harmless against zero weights)
    float mzA = fmaf(-Adrv2, SA.x - SA.y, Boff2);
    float mzB = fmaf(-Adrv2, SB.x - SB.y, Boff2);
    float acA = __fdividef(1.f, 1.f + exp2_f(mzA));
    float acB = __fdividef(1.f, 1.f + exp2_f(mzB));
    if (lid < NAC) acr[slot4 * 48 + lid] = bcu(pk2(acA, acB));

    // fb[c16]: row partial over 16 packed ACs -> 4 b128 + 16 pk_fma_f16
    const uint4* ab = (const uint4*)(acr + slot4 * 48 + (q << 4));
    uint4 A0 = ab[0], A1 = ab[1], A2 = ab[2], A3 = ab[3];
    v2h g0 = wfbh[0] * bch(A0.x);
    v2h g1 = wfbh[1] * bch(A0.y);
    g0 += wfbh[2]  * bch(A0.z);  g1 += wfbh[3]  * bch(A0.w);
    g0 += wfbh[4]  * bch(A1.x);  g1 += wfbh[5]  * bch(A1.y);
    g0 += wfbh[6]  * bch(A1.z);  g1 += wfbh[7]  * bch(A1.w);
    g0 += wfbh[8]  * bch(A2.x);  g1 += wfbh[9]  * bch(A2.y);
    g0 += wfbh[10] * bch(A2.z);  g1 += wfbh[11] * bch(A2.w);
    g0 += wfbh[12] * bch(A3.x);  g1 += wfbh[13] * bch(A3.y);
    g0 += wfbh[14] * bch(A3.z);  g1 += wfbh[15] * bch(A3.w);
    v2h gs = xsum32h(xsum16h(g0 + g1));       // sum 4 row partials, both chains
    float fbA = (float)gs[0], fbB = (float)gs[1];

    // BC + LNR sigmoids and pool recurrences (packed f32 per chain)
    float mlzA = fmaf(-slope2, xfA, soff2);
    float mpzA = fmaf(-slope2, fbA, mlzA);
    float mlzB = fmaf(-slope2, xfB, soff2);
    float mpzB = fmaf(-slope2, fbB, mlzB);
    f2 pvA, pvB;
    pvA.x = __fdividef(1.f, 1.f + exp2_f(mpzA));
    pvA.y = __fdividef(1.f, 1.f + exp2_f(mlzA));
    pvB.x = __fdividef(1.f, 1.f + exp2_f(mpzB));
    pvB.y = __fdividef(1.f, 1.f + exp2_f(mlzB));
    f2 p2A = poolA * (1.f - RHO) + RHO;
    f2 p2B = poolB * (1.f - RHO) + RHO;
    f2 rvA = pvA * p2A, rvB = pvB * p2B;
    poolA = p2A - rvA;  poolB = p2B - rvB;
    if (lid < NBC) {
      relr[lid] = bcu(pk2(rvA.x, rvB.x));
      if (emit) {
        int st = slot4 * NBC + lid;
        f2 t1; t1.x = osc_c * rvA.x; t1.y = osc_c * rvB.x; ybst[st] = t1;
        f2 t2; t2.x = fbA;           t2.y = fbB;           fbst[st] = t2;
        f2 t3; t3.x = osc_c * rvA.y; t3.y = osc_c * rvB.y; ylst[st] = t3;
      }
    }

    // u[lid]: 4 b128 + 14 pk_fma_f16
    const uint4* rb = (const uint4*)relr;
    uint4 R0 = rb[0], R1 = rb[1], R2 = rb[2], R3 = rb[3];
    v2h h0 = wuh[0] * bch(R0.x);
    v2h h1 = wuh[1] * bch(R0.y);
    h0 += wuh[2]  * bch(R0.z);  h1 += wuh[3]  * bch(R0.w);
    h0 += wuh[4]  * bch(R1.x);  h1 += wuh[5]  * bch(R1.y);
    h0 += wuh[6]  * bch(R1.z);  h1 += wuh[7]  * bch(R1.w);
    h0 += wuh[8]  * bch(R2.x);  h1 += wuh[9]  * bch(R2.y);
    h0 += wuh[10] * bch(R2.z);  h1 += wuh[11] * bch(R2.w);
    h0 += wuh[12] * bch(R3.x);  h1 += wuh[13] * bch(R3.y);
    v2h uh = h0 + h1;
    float uA = (float)uh[0], uB = (float)uh[1];
    if (lid < NAC) {
      u_ring[lid * RING + rslot] = bcu(uh);
      SA = SA * rv2 + (cn2 * uA - co2 * uoA);
      SB = SB * rv2 + (cn2 * uB - co2 * uoB);
    }
  };

  // ---- 4-step group: batched xf + ring reads ----
  auto group = [&](int s4, int r4, bool emit) __attribute__((always_inline)) {
    uint2 xa = *(const uint2*)&xf_lds[c16 * XPAD + s4];
    uint2 xb = *(const uint2*)&xf_lds[c16 * XPAD + s4 + CHC];
    int roff = ((lid < NAC) ? lid : 0) * RING + r4;
    uint4 ur = *(const uint4*)&u_ring[roff];
    v2h xA01 = bch(xa.x), xA23 = bch(xa.y);
    v2h xB01 = bch(xb.x), xB23 = bch(xb.y);
    v2h u0 = bch(ur.x), u1 = bch(ur.y), u2 = bch(ur.z), u3 = bch(ur.w);
    step(0, r4 + 0, (float)xA01[0], (float)xB01[0], (float)u0[0], (float)u0[1], emit);
    step(1, r4 + 1, (float)xA01[1], (float)xB01[1], (float)u1[0], (float)u1[1], emit);
    step(2, r4 + 2, (float)xA23[0], (float)xB23[0], (float)u2[0], (float)u2[1], emit);
    step(3, r4 + 3, (float)xA23[1], (float)xB23[1], (float)u3[0], (float)u3[1], emit);
  };

  // ---- warm phase ----
  int r4 = 0;
  for (int s4 = 0; s4 < WU; s4 += 4) {
    group(s4, r4, false);
    r4 += 4; if (r4 == RING) r4 = 0;
  }

  // chunk-0 exact start: reset chain A state and zero its ring halves
  if (firstA) {
    SA.x = 0.f; SA.y = 0.f;
    poolA.x = 1.f; poolA.y = 1.f;
    for (int i = lid; i < NAC * RING; i += 64) u_ring[i] &= 0xFFFF0000u;
  }

  // ---- emit phase ----
  for (int s4 = WU; s4 < NTW; s4 += 4) {
    group(s4, r4, true);
    r4 += 4; if (r4 == RING) r4 = 0;

    // flush 4 staged steps for both chains (coalesced, off critical path)
    asm volatile("" ::: "memory");
    int tgA = t0A + (s4 - WU);
    size_t obA = ((size_t)b * TT + tgA) * NBC;
    size_t oaA = ((size_t)b * TT + tgA) * NAC;
    if (lid < 4 * NBC) {
      f2 v1 = ybst[lid], v2_ = fbst[lid], v3 = ylst[lid];
      yb [obA + lid] = v1.x;  yb [obA + (size_t)CHC * NBC + lid] = v1.y;
      fbp[obA + lid] = v2_.x; fbp[obA + (size_t)CHC * NBC + lid] = v2_.y;
      ylp[obA + lid] = v3.x;  ylp[obA + (size_t)CHC * NBC + lid] = v3.y;
    }
    if (lid < NAC) {
#pragma unroll
      for (int sl = 0; sl < 4; ++sl) {
        v2h h = bch(acr[sl * 48 + lid]);
        acp[oaA + sl * NAC + lid] = (float)h[0];
        acp[oaA + (size_t)CHC * NAC + sl * NAC + lid] = (float)h[1];
      }
    }
    asm volatile("" ::: "memory");
  }
}

extern "C" void kernel_launch(void* const* d_in, const int* in_sizes, int n_in,
                              void* d_out, int out_size, void* d_ws, size_t ws_size,
                              hipStream_t stream) {
  (void)in_sizes; (void)n_in; (void)d_ws; (void)ws_size; (void)out_size;
  bcn_kernel<<<dim3(BB * NPAIR), dim3(64), 0, stream>>>(
      (const float*)d_in[0],  // x
      (const float*)d_in[1],  // bc_kernels
      (const float*)d_in[2],  // log_sigmoid_slope
      (const float*)d_in[3],  // sigmoid_offset
      (const float*)d_in[4],  // log_bc_ac_weight
      (const float*)d_in[5],  // log_ac_tau_rise
      (const float*)d_in[6],  // log_ac_tau_decay
      (const float*)d_in[7],  // log_ac_sigmoid_slope
      (const float*)d_in[8],  // ac_sigmoid_offset
      (const float*)d_in[9],  // log_ac_bc_weight
      (const float*)d_in[10], // out_scale
      (float*)d_out);
}